// Round 1
// baseline (666.756 us; speedup 1.0000x reference)
//
#include <hip/hip_runtime.h>

// GCN: out = head( agg(relu, b2, gemm(agg(relu, b1, gemm(x,W1)), W2)) )
// agg(i) = dis[i] * ( h[i]*dis[i] + sum_{e: dst=i} h[src_e]*dis[src_e] ) + b
// CSR by dst is rebuilt every call (same work each call; graph-capture safe).

static __device__ __forceinline__ float4 ld4(const float* p) {
    return *reinterpret_cast<const float4*>(p);
}

// ---------------- CSR build ----------------
__global__ void init_kernel(int* __restrict__ deg, int* __restrict__ cursor, int n) {
    int i = blockIdx.x * blockDim.x + threadIdx.x;
    if (i < n) { deg[i] = 1; cursor[i] = 0; }   // deg starts at 1: self-loop
}

__global__ void hist_kernel(const int* __restrict__ dstv, int* __restrict__ deg, int e) {
    int i = blockIdx.x * blockDim.x + threadIdx.x;
    if (i < e) atomicAdd(&deg[dstv[i]], 1);
}

__global__ void dis_kernel(const int* __restrict__ deg, float* __restrict__ dis, int n) {
    int i = blockIdx.x * blockDim.x + threadIdx.x;
    if (i < n) dis[i] = rsqrtf((float)deg[i]);  // deg>=1 always (self-loops)
}

__global__ void scan_block_sum(const int* __restrict__ deg, int* __restrict__ bsums, int n) {
    __shared__ int s[256];
    int i = blockIdx.x * 256 + threadIdx.x;
    s[threadIdx.x] = (i < n) ? (deg[i] - 1) : 0;   // edge count excl. self-loop
    __syncthreads();
    for (int o = 128; o > 0; o >>= 1) {
        if (threadIdx.x < o) s[threadIdx.x] += s[threadIdx.x + o];
        __syncthreads();
    }
    if (threadIdx.x == 0) bsums[blockIdx.x] = s[0];
}

__global__ void scan_bsums(const int* __restrict__ bsums, int* __restrict__ bexcl, int nb) {
    // nb <= 512 (N=100000 -> nb=391)
    __shared__ int s[512];
    int t = threadIdx.x;
    int v = (t < nb) ? bsums[t] : 0;
    s[t] = v; __syncthreads();
    for (int o = 1; o < 512; o <<= 1) {
        int x = (t >= o) ? s[t - o] : 0;
        __syncthreads();
        s[t] += x;
        __syncthreads();
    }
    if (t < nb) bexcl[t] = s[t] - v;  // exclusive
}

__global__ void scan_offsets(const int* __restrict__ deg, const int* __restrict__ bexcl,
                             int* __restrict__ offs, int n) {
    __shared__ int s[256];
    int t = threadIdx.x;
    int i = blockIdx.x * 256 + t;
    int v = (i < n) ? (deg[i] - 1) : 0;
    s[t] = v; __syncthreads();
    for (int o = 1; o < 256; o <<= 1) {
        int x = (t >= o) ? s[t - o] : 0;
        __syncthreads();
        s[t] += x;
        __syncthreads();
    }
    if (i < n) offs[i] = bexcl[blockIdx.x] + s[t] - v;  // exclusive global offset
}

__global__ void scatter_kernel(const int* __restrict__ srcv, const int* __restrict__ dstv,
                               const int* __restrict__ offs, int* __restrict__ cursor,
                               int* __restrict__ csr, int e) {
    int i = blockIdx.x * blockDim.x + threadIdx.x;
    if (i < e) {
        int d = dstv[i];
        int p = offs[d] + atomicAdd(&cursor[d], 1);
        csr[p] = srcv[i];
    }
}

// ---------------- GEMM: out[n x 128] = A[n x 128] @ W[128 x 128] ----------------
// Persistent blocks (1 block/CU; 96 KiB LDS), W resident, 64-row chunks,
// register prefetch of next chunk overlaps compute.
__global__ __launch_bounds__(512, 1)
void gemm_nn128(const float* __restrict__ A, const float* __restrict__ W,
                float* __restrict__ out, int n, int nchunk) {
    __shared__ float Ws[128 * 128];   // 64 KiB, [k][j]
    __shared__ float As[64 * 128];    // 32 KiB, [r][k]
    int tid = threadIdx.x;
#pragma unroll
    for (int q = 0; q < 8; ++q)
        ((float4*)Ws)[tid + 512 * q] = ((const float4*)W)[tid + 512 * q];

    int tc = tid & 31;   // col group -> cols tc*4 .. +3
    int tr = tid >> 5;   // row group -> rows tr*4 .. +3 (16 groups * 4 = 64 rows)
    int col0 = tc * 4;

    int c = blockIdx.x;
    float4 pf[4];
    if (c < nchunk) {
        int base = c * 64;
#pragma unroll
        for (int q = 0; q < 4; ++q) {
            int fidx = tid + 512 * q;             // float4 index into 64x128 tile
            int row = base + (fidx >> 5);
            if (row > n - 1) row = n - 1;
            pf[q] = ld4(A + (size_t)row * 128 + (fidx & 31) * 4);
        }
    }
    for (; c < nchunk; c += gridDim.x) {
        __syncthreads();                          // LDS free (W loaded / prev compute done)
#pragma unroll
        for (int q = 0; q < 4; ++q)
            ((float4*)As)[tid + 512 * q] = pf[q];
        __syncthreads();
        int cn = c + gridDim.x;                   // prefetch next chunk during compute
        if (cn < nchunk) {
            int base = cn * 64;
#pragma unroll
            for (int q = 0; q < 4; ++q) {
                int fidx = tid + 512 * q;
                int row = base + (fidx >> 5);
                if (row > n - 1) row = n - 1;
                pf[q] = ld4(A + (size_t)row * 128 + (fidx & 31) * 4);
            }
        }
        float4 acc[4];
#pragma unroll
        for (int r = 0; r < 4; ++r) acc[r] = make_float4(0.f, 0.f, 0.f, 0.f);
#pragma unroll 8
        for (int k4 = 0; k4 < 32; ++k4) {
            float4 av[4], wv[4];
#pragma unroll
            for (int r = 0; r < 4; ++r)
                av[r] = ld4(&As[(tr * 4 + r) * 128 + k4 * 4]);
#pragma unroll
            for (int kk = 0; kk < 4; ++kk)
                wv[kk] = ld4(&Ws[(k4 * 4 + kk) * 128 + col0]);
#pragma unroll
            for (int r = 0; r < 4; ++r) {
                acc[r].x += av[r].x * wv[0].x + av[r].y * wv[1].x + av[r].z * wv[2].x + av[r].w * wv[3].x;
                acc[r].y += av[r].x * wv[0].y + av[r].y * wv[1].y + av[r].z * wv[2].y + av[r].w * wv[3].y;
                acc[r].z += av[r].x * wv[0].z + av[r].y * wv[1].z + av[r].z * wv[2].z + av[r].w * wv[3].z;
                acc[r].w += av[r].x * wv[0].w + av[r].y * wv[1].w + av[r].z * wv[2].w + av[r].w * wv[3].w;
            }
        }
        int base = c * 64;
#pragma unroll
        for (int r = 0; r < 4; ++r) {
            int row = base + tr * 4 + r;
            if (row < n)
                *reinterpret_cast<float4*>(out + (size_t)row * 128 + col0) = acc[r];
        }
    }
}

// ---------------- Aggregation: node-parallel over CSR ----------------
template <bool RELU>
__global__ void agg_kernel(const float* __restrict__ h, const float* __restrict__ dis,
                           const int* __restrict__ offs, const int* __restrict__ deg,
                           const int* __restrict__ csr, const float* __restrict__ bias,
                           float* __restrict__ out, int n) {
    int node = blockIdx.x * 8 + (threadIdx.x >> 5);   // 8 nodes/block, 32 lanes/node
    if (node >= n) return;
    int l4 = (threadIdx.x & 31) * 4;
    float di = dis[node];
    float4 hv = ld4(h + (size_t)node * 128 + l4);
    float4 acc;                                       // self-loop term: h[i]*dis[i]
    acc.x = hv.x * di; acc.y = hv.y * di; acc.z = hv.z * di; acc.w = hv.w * di;
    int st = offs[node];
    int cnt = deg[node] - 1;
    int e = 0;
    for (; e + 1 < cnt; e += 2) {                     // 2-way unroll: two gathers in flight
        int s0 = csr[st + e], s1 = csr[st + e + 1];
        float d0 = dis[s0], d1 = dis[s1];
        float4 v0 = ld4(h + (size_t)s0 * 128 + l4);
        float4 v1 = ld4(h + (size_t)s1 * 128 + l4);
        acc.x += v0.x * d0 + v1.x * d1;
        acc.y += v0.y * d0 + v1.y * d1;
        acc.z += v0.z * d0 + v1.z * d1;
        acc.w += v0.w * d0 + v1.w * d1;
    }
    if (e < cnt) {
        int s0 = csr[st + e];
        float d0 = dis[s0];
        float4 v0 = ld4(h + (size_t)s0 * 128 + l4);
        acc.x += v0.x * d0; acc.y += v0.y * d0; acc.z += v0.z * d0; acc.w += v0.w * d0;
    }
    float4 b = ld4(bias + l4);
    float4 o;
    o.x = acc.x * di + b.x; o.y = acc.y * di + b.y;
    o.z = acc.z * di + b.z; o.w = acc.w * di + b.w;
    if (RELU) {
        o.x = fmaxf(o.x, 0.f); o.y = fmaxf(o.y, 0.f);
        o.z = fmaxf(o.z, 0.f); o.w = fmaxf(o.w, 0.f);
    }
    *reinterpret_cast<float4*>(out + (size_t)node * 128 + l4) = o;
}

// ---------------- Head: out[n x 40] = A[n x 128] @ Wl[128 x 40] + bl ----------------
__global__ __launch_bounds__(256)
void head_kernel(const float* __restrict__ A, const float* __restrict__ W,
                 const float* __restrict__ bias, float* __restrict__ out, int n) {
    __shared__ float Ws[128 * 40];   // 20 KiB
    __shared__ float bs[40];
    int tid = threadIdx.x;
#pragma unroll
    for (int q = 0; q < 5; ++q)
        ((float4*)Ws)[tid + 256 * q] = ((const float4*)W)[tid + 256 * q];
    if (tid < 40) bs[tid] = bias[tid];
    __syncthreads();

    int rg = tid >> 3;           // 0..31 -> 2 rows each: 64 rows/block
    int c0 = (tid & 7) * 5;      // 8 col groups * 5 = 40 cols
    int row0 = blockIdx.x * 64 + rg * 2;
    int rA = row0 < n ? row0 : n - 1;
    int rB = row0 + 1 < n ? row0 + 1 : n - 1;
    float acc[2][5];
#pragma unroll
    for (int r = 0; r < 2; ++r)
#pragma unroll
        for (int cc = 0; cc < 5; ++cc) acc[r][cc] = 0.f;
#pragma unroll 4
    for (int k4 = 0; k4 < 32; ++k4) {
        float4 a0 = ld4(A + (size_t)rA * 128 + k4 * 4);
        float4 a1 = ld4(A + (size_t)rB * 128 + k4 * 4);
        float ak[2][4] = {{a0.x, a0.y, a0.z, a0.w}, {a1.x, a1.y, a1.z, a1.w}};
#pragma unroll
        for (int kk = 0; kk < 4; ++kk) {
            int k = k4 * 4 + kk;
#pragma unroll
            for (int cc = 0; cc < 5; ++cc) {
                float w = Ws[k * 40 + c0 + cc];
                acc[0][cc] += ak[0][kk] * w;
                acc[1][cc] += ak[1][kk] * w;
            }
        }
    }
#pragma unroll
    for (int r = 0; r < 2; ++r) {
        int row = row0 + r;
        if (row < n) {
#pragma unroll
            for (int cc = 0; cc < 5; ++cc)
                out[(size_t)row * 40 + c0 + cc] = acc[r][cc] + bs[c0 + cc];
        }
    }
}

// ---------------- launch ----------------
extern "C" void kernel_launch(void* const* d_in, const int* in_sizes, int n_in,
                              void* d_out, int out_size, void* d_ws, size_t ws_size,
                              hipStream_t stream) {
    const float* x  = (const float*)d_in[0];
    const int*   ei = (const int*)d_in[1];
    const float* W1 = (const float*)d_in[2];
    const float* b1 = (const float*)d_in[3];
    const float* W2 = (const float*)d_in[4];
    const float* b2 = (const float*)d_in[5];
    const float* Wl = (const float*)d_in[6];
    const float* bl = (const float*)d_in[7];
    float* out = (float*)d_out;

    int n = in_sizes[0] / 128;
    int e = in_sizes[1] / 2;
    const int* srcv = ei;
    const int* dstv = ei + e;

    char* p = (char*)d_ws;
    auto carve = [&](size_t bytes) { char* r = p; p += (bytes + 255) & ~(size_t)255; return r; };
    int*   deg    = (int*)  carve((size_t)n * 4);
    float* dis    = (float*)carve((size_t)n * 4);
    int*   offs   = (int*)  carve((size_t)n * 4);
    int*   cursor = (int*)  carve((size_t)n * 4);
    int*   bsums  = (int*)  carve(512 * 4);
    int*   bexcl  = (int*)  carve(512 * 4);
    int*   csr    = (int*)  carve((size_t)e * 4);
    float* bufA   = (float*)carve((size_t)n * 128 * 4);
    float* bufB   = (float*)carve((size_t)n * 128 * 4);

    int nb = (n + 255) / 256;                 // 391 <= 512
    int nchunk = (n + 63) / 64;

    hipLaunchKernelGGL(init_kernel, dim3((n + 255) / 256), dim3(256), 0, stream, deg, cursor, n);
    hipLaunchKernelGGL(hist_kernel, dim3((e + 255) / 256), dim3(256), 0, stream, dstv, deg, e);
    hipLaunchKernelGGL(dis_kernel,  dim3((n + 255) / 256), dim3(256), 0, stream, deg, dis, n);
    hipLaunchKernelGGL(scan_block_sum, dim3(nb), dim3(256), 0, stream, deg, bsums, n);
    hipLaunchKernelGGL(scan_bsums, dim3(1), dim3(512), 0, stream, bsums, bexcl, nb);
    hipLaunchKernelGGL(scan_offsets, dim3(nb), dim3(256), 0, stream, deg, bexcl, offs, n);
    hipLaunchKernelGGL(scatter_kernel, dim3((e + 255) / 256), dim3(256), 0, stream,
                       srcv, dstv, offs, cursor, csr, e);

    // layer 1
    hipLaunchKernelGGL(gemm_nn128, dim3(256), dim3(512), 0, stream, x, W1, bufA, n, nchunk);
    hipLaunchKernelGGL(agg_kernel<true>, dim3((n + 7) / 8), dim3(256), 0, stream,
                       bufA, dis, offs, deg, csr, b1, bufB, n);
    // layer 2
    hipLaunchKernelGGL(gemm_nn128, dim3(256), dim3(512), 0, stream, bufB, W2, bufA, n, nchunk);
    hipLaunchKernelGGL(agg_kernel<true>, dim3((n + 7) / 8), dim3(256), 0, stream,
                       bufA, dis, offs, deg, csr, b2, bufB, n);
    // head
    hipLaunchKernelGGL(head_kernel, dim3((n + 63) / 64), dim3(256), 0, stream,
                       bufB, Wl, bl, out, n);
}

// Round 2
// 658.188 us; speedup vs baseline: 1.0130x; 1.0130x over previous
//
#include <hip/hip_runtime.h>

// GCN: out = head( agg(relu,b2, gemm(agg(relu,b1, gemm(x,W1)·dis), W2)·dis) )
// gemm epilogue scales row i by dis[i]  ->  hs[i] = (A@W)[i] * dis[i]
// agg(i) = relu( dis[i] * ( hs[i] + sum_{e: dst=i} hs[src_e] ) + b )
// CSR by dst rebuilt every call (same work per call; graph-capture safe).

static __device__ __forceinline__ float4 ld4(const float* p) {
    return *reinterpret_cast<const float4*>(p);
}

// ---------------- CSR build ----------------
__global__ void init_kernel(int* __restrict__ deg, int* __restrict__ cursor, int n) {
    int i = blockIdx.x * blockDim.x + threadIdx.x;
    if (i < n) { deg[i] = 1; cursor[i] = 0; }   // deg starts at 1: self-loop
}

__global__ void hist_kernel(const int* __restrict__ dstv, int* __restrict__ deg, int e) {
    int i4 = (blockIdx.x * blockDim.x + threadIdx.x) * 4;
    if (i4 + 3 < e) {
        int4 d = *reinterpret_cast<const int4*>(dstv + i4);
        atomicAdd(&deg[d.x], 1); atomicAdd(&deg[d.y], 1);
        atomicAdd(&deg[d.z], 1); atomicAdd(&deg[d.w], 1);
    } else {
        for (int k = i4; k < e; ++k) atomicAdd(&deg[dstv[k]], 1);
    }
}

// block-sums of (deg-1) + dis = rsqrt(deg)
__global__ void scan_block_sum(const int* __restrict__ deg, int* __restrict__ bsums,
                               float* __restrict__ dis, int n) {
    __shared__ int s[256];
    int i = blockIdx.x * 256 + threadIdx.x;
    int v = (i < n) ? (deg[i] - 1) : 0;
    if (i < n) dis[i] = rsqrtf((float)deg[i]);   // deg>=1 always (self-loops)
    s[threadIdx.x] = v;
    __syncthreads();
    for (int o = 128; o > 0; o >>= 1) {
        if (threadIdx.x < o) s[threadIdx.x] += s[threadIdx.x + o];
        __syncthreads();
    }
    if (threadIdx.x == 0) bsums[blockIdx.x] = s[0];
}

__global__ void scan_bsums(const int* __restrict__ bsums, int* __restrict__ bexcl, int nb) {
    // nb <= 512 (N=100000 -> nb=391)
    __shared__ int s[512];
    int t = threadIdx.x;
    int v = (t < nb) ? bsums[t] : 0;
    s[t] = v; __syncthreads();
    for (int o = 1; o < 512; o <<= 1) {
        int x = (t >= o) ? s[t - o] : 0;
        __syncthreads();
        s[t] += x;
        __syncthreads();
    }
    if (t < nb) bexcl[t] = s[t] - v;  // exclusive
}

__global__ void scan_offsets(const int* __restrict__ deg, const int* __restrict__ bexcl,
                             int* __restrict__ offs, int n) {
    __shared__ int s[256];
    int t = threadIdx.x;
    int i = blockIdx.x * 256 + t;
    int v = (i < n) ? (deg[i] - 1) : 0;
    s[t] = v; __syncthreads();
    for (int o = 1; o < 256; o <<= 1) {
        int x = (t >= o) ? s[t - o] : 0;
        __syncthreads();
        s[t] += x;
        __syncthreads();
    }
    if (i < n) offs[i] = bexcl[blockIdx.x] + s[t] - v;  // exclusive global offset
}

__global__ void scatter_kernel(const int* __restrict__ srcv, const int* __restrict__ dstv,
                               const int* __restrict__ offs, int* __restrict__ cursor,
                               int* __restrict__ csr, int e) {
    int i4 = (blockIdx.x * blockDim.x + threadIdx.x) * 4;
    if (i4 + 3 < e) {
        int4 sv = *reinterpret_cast<const int4*>(srcv + i4);
        int4 dv = *reinterpret_cast<const int4*>(dstv + i4);
        int p;
        p = offs[dv.x] + atomicAdd(&cursor[dv.x], 1); csr[p] = sv.x;
        p = offs[dv.y] + atomicAdd(&cursor[dv.y], 1); csr[p] = sv.y;
        p = offs[dv.z] + atomicAdd(&cursor[dv.z], 1); csr[p] = sv.z;
        p = offs[dv.w] + atomicAdd(&cursor[dv.w], 1); csr[p] = sv.w;
    } else {
        for (int k = i4; k < e; ++k) {
            int d = dstv[k];
            int p = offs[d] + atomicAdd(&cursor[d], 1);
            csr[p] = srcv[k];
        }
    }
}

// ---------------- GEMM: out[r] = (A[r] @ W) * rowscale[r],  128x128 W ----------------
// 1024 threads (16 waves/CU), 128-row chunks, W+A tiles resident (128 KiB LDS).
__global__ __launch_bounds__(1024, 1)
void gemm_nn128(const float* __restrict__ A, const float* __restrict__ W,
                const float* __restrict__ rowscale, float* __restrict__ out,
                int n, int nchunk) {
    __shared__ float Ws[128 * 128];   // [k][j], 64 KiB
    __shared__ float As[128 * 128];   // [r][k], 64 KiB
    int tid = threadIdx.x;
#pragma unroll
    for (int q = 0; q < 4; ++q)
        ((float4*)Ws)[tid + 1024 * q] = ((const float4*)W)[tid + 1024 * q];

    int tc = tid & 31;   // col group -> cols tc*4 .. +3
    int tr = tid >> 5;   // row group -> rows tr*4 .. +3 (32 groups * 4 = 128 rows)
    int col0 = tc * 4;

    int c = blockIdx.x;
    float4 pf[4];
    auto prefetch = [&](int cc) {
#pragma unroll
        for (int q = 0; q < 4; ++q) {
            int fidx = tid + 1024 * q;            // float4 index into 128x128 tile
            int row = cc * 128 + (fidx >> 5);
            if (row > n - 1) row = n - 1;
            pf[q] = ld4(A + (size_t)row * 128 + (fidx & 31) * 4);
        }
    };
    if (c < nchunk) prefetch(c);
    for (; c < nchunk; c += gridDim.x) {
        __syncthreads();                          // prev compute done (and Ws loaded)
#pragma unroll
        for (int q = 0; q < 4; ++q)
            ((float4*)As)[tid + 1024 * q] = pf[q];
        __syncthreads();
        if (c + (int)gridDim.x < nchunk) prefetch(c + gridDim.x);
        float4 acc[4];
#pragma unroll
        for (int r = 0; r < 4; ++r) acc[r] = make_float4(0.f, 0.f, 0.f, 0.f);
#pragma unroll 8
        for (int k4 = 0; k4 < 32; ++k4) {
            float4 av[4], wv[4];
#pragma unroll
            for (int r = 0; r < 4; ++r)
                av[r] = ld4(&As[(tr * 4 + r) * 128 + k4 * 4]);   // half-wave uniform -> LDS broadcast
#pragma unroll
            for (int kk = 0; kk < 4; ++kk)
                wv[kk] = ld4(&Ws[(k4 * 4 + kk) * 128 + col0]);
#pragma unroll
            for (int r = 0; r < 4; ++r) {
                acc[r].x += av[r].x * wv[0].x + av[r].y * wv[1].x + av[r].z * wv[2].x + av[r].w * wv[3].x;
                acc[r].y += av[r].x * wv[0].y + av[r].y * wv[1].y + av[r].z * wv[2].y + av[r].w * wv[3].y;
                acc[r].z += av[r].x * wv[0].z + av[r].y * wv[1].z + av[r].z * wv[2].z + av[r].w * wv[3].z;
                acc[r].w += av[r].x * wv[0].w + av[r].y * wv[1].w + av[r].z * wv[2].w + av[r].w * wv[3].w;
            }
        }
#pragma unroll
        for (int r = 0; r < 4; ++r) {
            int row = c * 128 + tr * 4 + r;
            if (row < n) {
                float s = rowscale[row];
                acc[r].x *= s; acc[r].y *= s; acc[r].z *= s; acc[r].w *= s;
                *reinterpret_cast<float4*>(out + (size_t)row * 128 + col0) = acc[r];
            }
        }
    }
}

// ---------------- Aggregation: node-parallel over CSR ----------------
// hs rows are pre-scaled by dis[src]; inner loop is a pure gather+add with
// indices broadcast from a cooperative coalesced load (4 gathers in flight).
template <bool RELU>
__global__ __launch_bounds__(256)
void agg_kernel(const float* __restrict__ hs, const float* __restrict__ dis,
                const int* __restrict__ offs, const int* __restrict__ deg,
                const int* __restrict__ csr, const float* __restrict__ bias,
                float* __restrict__ out, int n, int etot) {
    int node = blockIdx.x * 8 + (threadIdx.x >> 5);   // 8 nodes/block, 32 lanes/node
    if (node >= n) return;
    int lane = threadIdx.x & 31;
    int l4 = lane * 4;
    float di = dis[node];
    float4 acc = ld4(hs + (size_t)node * 128 + l4);   // self term (pre-scaled)
    int st = offs[node];
    int cnt = deg[node] - 1;
    for (int base = 0; base < cnt; base += 32) {
        int ii = st + base + lane;
        int iv = csr[ii < etot ? ii : etot - 1];      // coalesced block of indices
        int m = cnt - base; m = m > 32 ? 32 : m;
        int e = 0;
        for (; e + 4 <= m; e += 4) {
            int s0 = __shfl(iv, e, 32),     s1 = __shfl(iv, e + 1, 32);
            int s2 = __shfl(iv, e + 2, 32), s3 = __shfl(iv, e + 3, 32);
            float4 v0 = ld4(hs + (size_t)s0 * 128 + l4);
            float4 v1 = ld4(hs + (size_t)s1 * 128 + l4);
            float4 v2 = ld4(hs + (size_t)s2 * 128 + l4);
            float4 v3 = ld4(hs + (size_t)s3 * 128 + l4);
            acc.x += (v0.x + v1.x) + (v2.x + v3.x);
            acc.y += (v0.y + v1.y) + (v2.y + v3.y);
            acc.z += (v0.z + v1.z) + (v2.z + v3.z);
            acc.w += (v0.w + v1.w) + (v2.w + v3.w);
        }
        for (; e < m; ++e) {
            int s0 = __shfl(iv, e, 32);
            float4 v0 = ld4(hs + (size_t)s0 * 128 + l4);
            acc.x += v0.x; acc.y += v0.y; acc.z += v0.z; acc.w += v0.w;
        }
    }
    float4 b = ld4(bias + l4);
    float4 o;
    o.x = acc.x * di + b.x; o.y = acc.y * di + b.y;
    o.z = acc.z * di + b.z; o.w = acc.w * di + b.w;
    if (RELU) {
        o.x = fmaxf(o.x, 0.f); o.y = fmaxf(o.y, 0.f);
        o.z = fmaxf(o.z, 0.f); o.w = fmaxf(o.w, 0.f);
    }
    *reinterpret_cast<float4*>(out + (size_t)node * 128 + l4) = o;
}

// ---------------- Head: out[n x 40] = A[n x 128] @ Wl[128 x 40] + bl ----------------
__global__ __launch_bounds__(256)
void head_kernel(const float* __restrict__ A, const float* __restrict__ W,
                 const float* __restrict__ bias, float* __restrict__ out, int n) {
    __shared__ float Ws[128 * 40];   // 20 KiB
    __shared__ float bs[40];
    int tid = threadIdx.x;
#pragma unroll
    for (int q = 0; q < 5; ++q)
        ((float4*)Ws)[tid + 256 * q] = ((const float4*)W)[tid + 256 * q];
    if (tid < 40) bs[tid] = bias[tid];
    __syncthreads();

    int rg = tid >> 3;           // 0..31 -> 2 rows each: 64 rows/block
    int c0 = (tid & 7) * 5;      // 8 col groups * 5 = 40 cols
    int row0 = blockIdx.x * 64 + rg * 2;
    int rA = row0 < n ? row0 : n - 1;
    int rB = row0 + 1 < n ? row0 + 1 : n - 1;
    float acc[2][5];
#pragma unroll
    for (int r = 0; r < 2; ++r)
#pragma unroll
        for (int cc = 0; cc < 5; ++cc) acc[r][cc] = 0.f;
#pragma unroll 4
    for (int k4 = 0; k4 < 32; ++k4) {
        float4 a0 = ld4(A + (size_t)rA * 128 + k4 * 4);
        float4 a1 = ld4(A + (size_t)rB * 128 + k4 * 4);
        float ak[2][4] = {{a0.x, a0.y, a0.z, a0.w}, {a1.x, a1.y, a1.z, a1.w}};
#pragma unroll
        for (int kk = 0; kk < 4; ++kk) {
            int k = k4 * 4 + kk;
#pragma unroll
            for (int cc = 0; cc < 5; ++cc) {
                float w = Ws[k * 40 + c0 + cc];
                acc[0][cc] += ak[0][kk] * w;
                acc[1][cc] += ak[1][kk] * w;
            }
        }
    }
#pragma unroll
    for (int r = 0; r < 2; ++r) {
        int row = row0 + r;
        if (row < n) {
#pragma unroll
            for (int cc = 0; cc < 5; ++cc)
                out[(size_t)row * 40 + c0 + cc] = acc[r][cc] + bs[c0 + cc];
        }
    }
}

// ---------------- launch ----------------
extern "C" void kernel_launch(void* const* d_in, const int* in_sizes, int n_in,
                              void* d_out, int out_size, void* d_ws, size_t ws_size,
                              hipStream_t stream) {
    const float* x  = (const float*)d_in[0];
    const int*   ei = (const int*)d_in[1];
    const float* W1 = (const float*)d_in[2];
    const float* b1 = (const float*)d_in[3];
    const float* W2 = (const float*)d_in[4];
    const float* b2 = (const float*)d_in[5];
    const float* Wl = (const float*)d_in[6];
    const float* bl = (const float*)d_in[7];
    float* out = (float*)d_out;

    int n = in_sizes[0] / 128;
    int e = in_sizes[1] / 2;
    const int* srcv = ei;
    const int* dstv = ei + e;

    char* p = (char*)d_ws;
    auto carve = [&](size_t bytes) { char* r = p; p += (bytes + 255) & ~(size_t)255; return r; };
    int*   deg    = (int*)  carve((size_t)n * 4);
    float* dis    = (float*)carve((size_t)n * 4);
    int*   offs   = (int*)  carve((size_t)n * 4);
    int*   cursor = (int*)  carve((size_t)n * 4);
    int*   bsums  = (int*)  carve(512 * 4);
    int*   bexcl  = (int*)  carve(512 * 4);
    int*   csr    = (int*)  carve((size_t)e * 4);
    float* bufA   = (float*)carve((size_t)n * 128 * 4);
    float* bufB   = (float*)carve((size_t)n * 128 * 4);

    int nb = (n + 255) / 256;                 // 391 <= 512
    int nchunk = (n + 127) / 128;
    int e4b = (e / 4 + 255) / 256 + 1;        // blocks for 4-wide edge kernels

    hipLaunchKernelGGL(init_kernel, dim3((n + 255) / 256), dim3(256), 0, stream, deg, cursor, n);
    hipLaunchKernelGGL(hist_kernel, dim3(e4b), dim3(256), 0, stream, dstv, deg, e);
    hipLaunchKernelGGL(scan_block_sum, dim3(nb), dim3(256), 0, stream, deg, bsums, dis, n);
    hipLaunchKernelGGL(scan_bsums, dim3(1), dim3(512), 0, stream, bsums, bexcl, nb);
    hipLaunchKernelGGL(scan_offsets, dim3(nb), dim3(256), 0, stream, deg, bexcl, offs, n);
    hipLaunchKernelGGL(scatter_kernel, dim3(e4b), dim3(256), 0, stream,
                       srcv, dstv, offs, cursor, csr, e);

    // layer 1: bufA = (x@W1)*dis ; bufB = relu(agg(bufA)*dis + b1)
    hipLaunchKernelGGL(gemm_nn128, dim3(256), dim3(1024), 0, stream, x, W1, dis, bufA, n, nchunk);
    hipLaunchKernelGGL(agg_kernel<true>, dim3((n + 7) / 8), dim3(256), 0, stream,
                       bufA, dis, offs, deg, csr, b1, bufB, n, e);
    // layer 2
    hipLaunchKernelGGL(gemm_nn128, dim3(256), dim3(1024), 0, stream, bufB, W2, dis, bufA, n, nchunk);
    hipLaunchKernelGGL(agg_kernel<true>, dim3((n + 7) / 8), dim3(256), 0, stream,
                       bufA, dis, offs, deg, csr, b2, bufB, n, e);
    // head
    hipLaunchKernelGGL(head_kernel, dim3((n + 63) / 64), dim3(256), 0, stream,
                       bufB, Wl, bl, out, n);
}

// Round 4
// 553.607 us; speedup vs baseline: 1.2044x; 1.1889x over previous
//
#include <hip/hip_runtime.h>

// GCN with fp16 intermediate buffers (fp32 accumulate; threshold is bf16-grade).
// hs = (A@W)*dis stored fp16; agg(i) = relu(dis[i]*(hs[i]+sum_{src->i} hs[src]) + b) -> fp16.
// CSR rebuilt every call with init_kernel (NO hipMemsetAsync: graph-capture-safe,
// proven in round 2). All gathered indices clamped so no read can leave written ws.

typedef _Float16 half_t;
union H4 { short4 s; half_t h[4]; };
union H8 { int4 s; half_t h[8]; };

static __device__ __forceinline__ float4 ld4(const float* p) {
    return *reinterpret_cast<const float4*>(p);
}
static __device__ __forceinline__ short4 ldh4(const half_t* p) {
    return *reinterpret_cast<const short4*>(p);
}

// ---------------- CSR build (round-2 proven structure) ----------------
__global__ void init_kernel(int* __restrict__ deg, int* __restrict__ cursor, int n) {
    int i = blockIdx.x * blockDim.x + threadIdx.x;
    if (i < n) { deg[i] = 1; cursor[i] = 0; }   // deg starts at 1: self-loop
}

__global__ void hist_kernel(const int* __restrict__ dstv, int* __restrict__ deg, int e) {
    int i4 = (blockIdx.x * blockDim.x + threadIdx.x) * 4;
    if (i4 + 3 < e) {
        int4 d = *reinterpret_cast<const int4*>(dstv + i4);
        atomicAdd(&deg[d.x], 1); atomicAdd(&deg[d.y], 1);
        atomicAdd(&deg[d.z], 1); atomicAdd(&deg[d.w], 1);
    } else {
        for (int k = i4; k < e; ++k) atomicAdd(&deg[dstv[k]], 1);
    }
}

// block-sums of (deg-1) + dis = rsqrt(deg)
__global__ void scan_block_sum(const int* __restrict__ deg, int* __restrict__ bsums,
                               float* __restrict__ dis, int n) {
    __shared__ int s[256];
    int i = blockIdx.x * 256 + threadIdx.x;
    int v = (i < n) ? (deg[i] - 1) : 0;
    if (i < n) dis[i] = rsqrtf((float)deg[i]);   // deg>=1 always
    s[threadIdx.x] = v;
    __syncthreads();
    for (int o = 128; o > 0; o >>= 1) {
        if (threadIdx.x < o) s[threadIdx.x] += s[threadIdx.x + o];
        __syncthreads();
    }
    if (threadIdx.x == 0) bsums[blockIdx.x] = s[0];
}

__global__ void scan_bsums(const int* __restrict__ bsums, int* __restrict__ bexcl, int nb) {
    __shared__ int s[512];
    int t = threadIdx.x;
    int v = (t < nb) ? bsums[t] : 0;
    s[t] = v; __syncthreads();
    for (int o = 1; o < 512; o <<= 1) {
        int x = (t >= o) ? s[t - o] : 0;
        __syncthreads();
        s[t] += x;
        __syncthreads();
    }
    if (t < nb) bexcl[t] = s[t] - v;  // exclusive
}

__global__ void scan_offsets(const int* __restrict__ deg, const int* __restrict__ bexcl,
                             int* __restrict__ offs, int n) {
    __shared__ int s[256];
    int t = threadIdx.x;
    int i = blockIdx.x * 256 + t;
    int v = (i < n) ? (deg[i] - 1) : 0;
    s[t] = v; __syncthreads();
    for (int o = 1; o < 256; o <<= 1) {
        int x = (t >= o) ? s[t - o] : 0;
        __syncthreads();
        s[t] += x;
        __syncthreads();
    }
    if (i < n) offs[i] = bexcl[blockIdx.x] + s[t] - v;  // exclusive global offset
}

__global__ void scatter_kernel(const int* __restrict__ srcv, const int* __restrict__ dstv,
                               const int* __restrict__ offs, int* __restrict__ cursor,
                               int* __restrict__ csr, int e) {
    int i4 = (blockIdx.x * blockDim.x + threadIdx.x) * 4;
    if (i4 + 3 < e) {
        int4 sv = *reinterpret_cast<const int4*>(srcv + i4);
        int4 dv = *reinterpret_cast<const int4*>(dstv + i4);
        int p;
        p = offs[dv.x] + atomicAdd(&cursor[dv.x], 1); csr[p] = sv.x;
        p = offs[dv.y] + atomicAdd(&cursor[dv.y], 1); csr[p] = sv.y;
        p = offs[dv.z] + atomicAdd(&cursor[dv.z], 1); csr[p] = sv.z;
        p = offs[dv.w] + atomicAdd(&cursor[dv.w], 1); csr[p] = sv.w;
    } else {
        for (int k = i4; k < e; ++k) {
            int d = dstv[k];
            int p = offs[d] + atomicAdd(&cursor[d], 1);
            csr[p] = srcv[k];
        }
    }
}

// ---------------- GEMM: out[r] = fp16( (A[r] @ W) * rowscale[r] ), W 128x128 ----------------
template <typename AT>
__global__ __launch_bounds__(1024, 1)
void gemm_nn128(const AT* __restrict__ A, const float* __restrict__ W,
                const float* __restrict__ rowscale, half_t* __restrict__ out,
                int n, int nchunk) {
    __shared__ float Ws[128 * 128];   // [k][j], 64 KiB
    __shared__ float As[128 * 128];   // [r][k], 64 KiB
    constexpr bool HALF = (sizeof(AT) == 2);
    int tid = threadIdx.x;
#pragma unroll
    for (int q = 0; q < 4; ++q)
        ((float4*)Ws)[tid + 1024 * q] = ((const float4*)W)[tid + 1024 * q];

    int tc = tid & 31;
    int tr = tid >> 5;
    int col0 = tc * 4;

    int4 pf[4];
    auto prefetch = [&](int cc) {
        if constexpr (HALF) {
#pragma unroll
            for (int q = 0; q < 2; ++q) {
                int u = tid + 1024 * q;           // 16B unit: 8 halves; 16 units/row
                int row = cc * 128 + (u >> 4);
                if (row > n - 1) row = n - 1;
                pf[q] = *reinterpret_cast<const int4*>(
                    (const half_t*)A + (size_t)row * 128 + (u & 15) * 8);
            }
        } else {
#pragma unroll
            for (int q = 0; q < 4; ++q) {
                int fidx = tid + 1024 * q;        // float4 unit; 32 units/row
                int row = cc * 128 + (fidx >> 5);
                if (row > n - 1) row = n - 1;
                pf[q] = *reinterpret_cast<const int4*>(
                    (const float*)A + (size_t)row * 128 + (fidx & 31) * 4);
            }
        }
    };

    int c = blockIdx.x;
    if (c < nchunk) prefetch(c);
    for (; c < nchunk; c += gridDim.x) {
        __syncthreads();
        if constexpr (HALF) {
#pragma unroll
            for (int q = 0; q < 2; ++q) {
                int u = tid + 1024 * q;
                int r = u >> 4, cc = (u & 15) * 8;
                H8 hh; hh.s = pf[q];
#pragma unroll
                for (int j = 0; j < 8; ++j) As[r * 128 + cc + j] = (float)hh.h[j];
            }
        } else {
#pragma unroll
            for (int q = 0; q < 4; ++q)
                ((int4*)As)[tid + 1024 * q] = pf[q];
        }
        __syncthreads();
        if (c + (int)gridDim.x < nchunk) prefetch(c + gridDim.x);
        float4 acc[4];
#pragma unroll
        for (int r = 0; r < 4; ++r) acc[r] = make_float4(0.f, 0.f, 0.f, 0.f);
#pragma unroll 8
        for (int k4 = 0; k4 < 32; ++k4) {
            float4 av[4], wv[4];
#pragma unroll
            for (int r = 0; r < 4; ++r)
                av[r] = ld4(&As[(tr * 4 + r) * 128 + k4 * 4]);
#pragma unroll
            for (int kk = 0; kk < 4; ++kk)
                wv[kk] = ld4(&Ws[(k4 * 4 + kk) * 128 + col0]);
#pragma unroll
            for (int r = 0; r < 4; ++r) {
                acc[r].x += av[r].x * wv[0].x + av[r].y * wv[1].x + av[r].z * wv[2].x + av[r].w * wv[3].x;
                acc[r].y += av[r].x * wv[0].y + av[r].y * wv[1].y + av[r].z * wv[2].y + av[r].w * wv[3].y;
                acc[r].z += av[r].x * wv[0].z + av[r].y * wv[1].z + av[r].z * wv[2].z + av[r].w * wv[3].z;
                acc[r].w += av[r].x * wv[0].w + av[r].y * wv[1].w + av[r].z * wv[2].w + av[r].w * wv[3].w;
            }
        }
#pragma unroll
        for (int r = 0; r < 4; ++r) {
            int row = c * 128 + tr * 4 + r;
            if (row < n) {
                float s = rowscale[row];
                H4 o;
                o.h[0] = (half_t)(acc[r].x * s); o.h[1] = (half_t)(acc[r].y * s);
                o.h[2] = (half_t)(acc[r].z * s); o.h[3] = (half_t)(acc[r].w * s);
                *reinterpret_cast<short4*>(out + (size_t)row * 128 + col0) = o.s;
            }
        }
    }
}

// ---------------- Aggregation: node-parallel over CSR, fp16 rows ----------------
__global__ __launch_bounds__(256)
void agg_kernel(const half_t* __restrict__ hs, const float* __restrict__ dis,
                const int* __restrict__ offs, const int* __restrict__ deg,
                const int* __restrict__ csr, const float* __restrict__ bias,
                half_t* __restrict__ out, int n, int etot) {
    int node = blockIdx.x * 8 + (threadIdx.x >> 5);   // 8 nodes/block, 32 lanes/node
    if (node >= n) return;
    int lane = threadIdx.x & 31;
    int l4 = lane * 4;                                // half-index within row
    float di = dis[node];
    H4 sv; sv.s = ldh4(hs + (size_t)node * 128 + l4);
    float4 acc;
    acc.x = (float)sv.h[0]; acc.y = (float)sv.h[1];
    acc.z = (float)sv.h[2]; acc.w = (float)sv.h[3];
    int st = offs[node];
    int cnt = deg[node] - 1;
    // clamp so no index can ever leave the written region (defense vs any corruption)
    auto clampn = [&](int s) { return ((unsigned)s >= (unsigned)n) ? 0 : s; };
    for (int base = 0; base < cnt; base += 32) {
        int ii = st + base + lane;
        int iv = csr[ii < etot ? ii : etot - 1];      // coalesced index block
        int m = cnt - base; m = m > 32 ? 32 : m;
        int e = 0;
        for (; e + 4 <= m; e += 4) {
            int s0 = clampn(__shfl(iv, e, 32)),     s1 = clampn(__shfl(iv, e + 1, 32));
            int s2 = clampn(__shfl(iv, e + 2, 32)), s3 = clampn(__shfl(iv, e + 3, 32));
            H4 v0, v1, v2, v3;
            v0.s = ldh4(hs + (size_t)s0 * 128 + l4);
            v1.s = ldh4(hs + (size_t)s1 * 128 + l4);
            v2.s = ldh4(hs + (size_t)s2 * 128 + l4);
            v3.s = ldh4(hs + (size_t)s3 * 128 + l4);
            acc.x += ((float)v0.h[0] + (float)v1.h[0]) + ((float)v2.h[0] + (float)v3.h[0]);
            acc.y += ((float)v0.h[1] + (float)v1.h[1]) + ((float)v2.h[1] + (float)v3.h[1]);
            acc.z += ((float)v0.h[2] + (float)v1.h[2]) + ((float)v2.h[2] + (float)v3.h[2]);
            acc.w += ((float)v0.h[3] + (float)v1.h[3]) + ((float)v2.h[3] + (float)v3.h[3]);
        }
        for (; e < m; ++e) {
            int s0 = clampn(__shfl(iv, e, 32));
            H4 v0; v0.s = ldh4(hs + (size_t)s0 * 128 + l4);
            acc.x += (float)v0.h[0]; acc.y += (float)v0.h[1];
            acc.z += (float)v0.h[2]; acc.w += (float)v0.h[3];
        }
    }
    float4 b = ld4(bias + l4);
    float ox = fmaxf(acc.x * di + b.x, 0.f);
    float oy = fmaxf(acc.y * di + b.y, 0.f);
    float oz = fmaxf(acc.z * di + b.z, 0.f);
    float ow = fmaxf(acc.w * di + b.w, 0.f);
    H4 o;
    o.h[0] = (half_t)ox; o.h[1] = (half_t)oy; o.h[2] = (half_t)oz; o.h[3] = (half_t)ow;
    *reinterpret_cast<short4*>(out + (size_t)node * 128 + l4) = o.s;
}

// ---------------- Head: out[n x 40] = A(fp16)[n x 128] @ Wl[128 x 40] + bl ----------------
__global__ __launch_bounds__(256)
void head_kernel(const half_t* __restrict__ A, const float* __restrict__ W,
                 const float* __restrict__ bias, float* __restrict__ out, int n) {
    __shared__ float Ws[128 * 40];   // 20 KiB
    __shared__ float bs[40];
    int tid = threadIdx.x;
#pragma unroll
    for (int q = 0; q < 5; ++q)
        ((float4*)Ws)[tid + 256 * q] = ((const float4*)W)[tid + 256 * q];
    if (tid < 40) bs[tid] = bias[tid];
    __syncthreads();

    int rg = tid >> 3;           // 32 row groups * 2 rows = 64 rows/block
    int c0 = (tid & 7) * 5;      // 8 col groups * 5 = 40 cols
    int row0 = blockIdx.x * 64 + rg * 2;
    int rA = row0 < n ? row0 : n - 1;
    int rB = row0 + 1 < n ? row0 + 1 : n - 1;
    float acc[2][5];
#pragma unroll
    for (int r = 0; r < 2; ++r)
#pragma unroll
        for (int cc = 0; cc < 5; ++cc) acc[r][cc] = 0.f;
#pragma unroll 4
    for (int k4 = 0; k4 < 32; ++k4) {
        H4 a0, a1;
        a0.s = ldh4(A + (size_t)rA * 128 + k4 * 4);
        a1.s = ldh4(A + (size_t)rB * 128 + k4 * 4);
#pragma unroll
        for (int kk = 0; kk < 4; ++kk) {
            int k = k4 * 4 + kk;
            float f0 = (float)a0.h[kk], f1 = (float)a1.h[kk];
#pragma unroll
            for (int cc = 0; cc < 5; ++cc) {
                float w = Ws[k * 40 + c0 + cc];
                acc[0][cc] += f0 * w;
                acc[1][cc] += f1 * w;
            }
        }
    }
#pragma unroll
    for (int r = 0; r < 2; ++r) {
        int row = row0 + r;
        if (row < n) {
#pragma unroll
            for (int cc = 0; cc < 5; ++cc)
                out[(size_t)row * 40 + c0 + cc] = acc[r][cc] + bs[c0 + cc];
        }
    }
}

// ---------------- launch ----------------
extern "C" void kernel_launch(void* const* d_in, const int* in_sizes, int n_in,
                              void* d_out, int out_size, void* d_ws, size_t ws_size,
                              hipStream_t stream) {
    const float* x  = (const float*)d_in[0];
    const int*   ei = (const int*)d_in[1];
    const float* W1 = (const float*)d_in[2];
    const float* b1 = (const float*)d_in[3];
    const float* W2 = (const float*)d_in[4];
    const float* b2 = (const float*)d_in[5];
    const float* Wl = (const float*)d_in[6];
    const float* bl = (const float*)d_in[7];
    float* out = (float*)d_out;

    int n = in_sizes[0] / 128;
    int e = in_sizes[1] / 2;
    const int* srcv = ei;
    const int* dstv = ei + e;

    char* p = (char*)d_ws;
    auto carve = [&](size_t bytes) { char* r = p; p += (bytes + 255) & ~(size_t)255; return r; };
    int*    deg    = (int*)   carve((size_t)n * 4);
    float*  dis    = (float*) carve((size_t)n * 4);
    int*    offs   = (int*)   carve((size_t)n * 4);
    int*    cursor = (int*)   carve((size_t)n * 4);
    int*    bsums  = (int*)   carve(512 * 4);
    int*    bexcl  = (int*)   carve(512 * 4);
    int*    csr    = (int*)   carve((size_t)e * 4);
    half_t* bufA   = (half_t*)carve((size_t)n * 128 * 2);
    half_t* bufB   = (half_t*)carve((size_t)n * 128 * 2);

    int nb = (n + 255) / 256;                 // 391 <= 512
    int nchunk = (n + 127) / 128;
    int e4b = (e / 4 + 255) / 256 + 1;

    hipLaunchKernelGGL(init_kernel, dim3((n + 255) / 256), dim3(256), 0, stream, deg, cursor, n);
    hipLaunchKernelGGL(hist_kernel, dim3(e4b), dim3(256), 0, stream, dstv, deg, e);
    hipLaunchKernelGGL(scan_block_sum, dim3(nb), dim3(256), 0, stream, deg, bsums, dis, n);
    hipLaunchKernelGGL(scan_bsums, dim3(1), dim3(512), 0, stream, bsums, bexcl, nb);
    hipLaunchKernelGGL(scan_offsets, dim3(nb), dim3(256), 0, stream, deg, bexcl, offs, n);
    hipLaunchKernelGGL(scatter_kernel, dim3(e4b), dim3(256), 0, stream,
                       srcv, dstv, offs, cursor, csr, e);

    // layer 1
    hipLaunchKernelGGL(gemm_nn128<float>, dim3(256), dim3(1024), 0, stream,
                       x, W1, dis, bufA, n, nchunk);
    hipLaunchKernelGGL(agg_kernel, dim3((n + 7) / 8), dim3(256), 0, stream,
                       bufA, dis, offs, deg, csr, b1, bufB, n, e);
    // layer 2
    hipLaunchKernelGGL(gemm_nn128<half_t>, dim3(256), dim3(1024), 0, stream,
                       bufB, W2, dis, bufA, n, nchunk);
    hipLaunchKernelGGL(agg_kernel, dim3((n + 7) / 8), dim3(256), 0, stream,
                       bufA, dis, offs, deg, csr, b2, bufB, n, e);
    // head
    hipLaunchKernelGGL(head_kernel, dim3((n + 63) / 64), dim3(256), 0, stream,
                       bufB, Wl, bl, out, n);
}

// Round 7
// 549.040 us; speedup vs baseline: 1.2144x; 1.0083x over previous
//
#include <hip/hip_runtime.h>

// GCN with fp16 intermediate buffers (fp32 accumulate; threshold is bf16-grade).
// hs = (A@W)*dis stored fp16; agg(i) = relu(dis[i]*(hs[i]+sum_{src->i} hs[src]) + b) -> fp16.
// Round-5 change: non-temporal loads/stores on all STREAMING traffic (edge lists,
// csr scatter, once-read GEMM A) so L2 keeps the reused data (csr lines, hs gather
// table). Targets scatter's 108 MB write-amplification (full-line write-backs of
// randomly scattered 4B stores evicted by streaming reads).

typedef _Float16 half_t;
typedef int   v4i __attribute__((ext_vector_type(4)));
union H4 { short4 s; half_t h[4]; };
union H8 { v4i v; half_t h[8]; };

static __device__ __forceinline__ float4 ld4(const float* p) {
    return *reinterpret_cast<const float4*>(p);
}
static __device__ __forceinline__ short4 ldh4(const half_t* p) {
    return *reinterpret_cast<const short4*>(p);
}
static __device__ __forceinline__ v4i nt_ld4i(const int* p) {
    return __builtin_nontemporal_load(reinterpret_cast<const v4i*>(p));
}

// ---------------- CSR build ----------------
__global__ void init_kernel(int* __restrict__ deg, int* __restrict__ cursor, int n) {
    int i = blockIdx.x * blockDim.x + threadIdx.x;
    if (i < n) { deg[i] = 1; cursor[i] = 0; }   // deg starts at 1: self-loop
}

__global__ void hist_kernel(const int* __restrict__ dstv, int* __restrict__ deg, int e) {
    int i4 = (blockIdx.x * blockDim.x + threadIdx.x) * 4;
    if (i4 + 3 < e) {
        v4i d = nt_ld4i(dstv + i4);
        atomicAdd(&deg[d.x], 1); atomicAdd(&deg[d.y], 1);
        atomicAdd(&deg[d.z], 1); atomicAdd(&deg[d.w], 1);
    } else {
        for (int k = i4; k < e; ++k) atomicAdd(&deg[__builtin_nontemporal_load(dstv + k)], 1);
    }
}

// block-sums of (deg-1) + dis = rsqrt(deg)
__global__ void scan_block_sum(const int* __restrict__ deg, int* __restrict__ bsums,
                               float* __restrict__ dis, int n) {
    __shared__ int s[256];
    int i = blockIdx.x * 256 + threadIdx.x;
    int v = (i < n) ? (deg[i] - 1) : 0;
    if (i < n) dis[i] = rsqrtf((float)deg[i]);   // deg>=1 always
    s[threadIdx.x] = v;
    __syncthreads();
    for (int o = 128; o > 0; o >>= 1) {
        if (threadIdx.x < o) s[threadIdx.x] += s[threadIdx.x + o];
        __syncthreads();
    }
    if (threadIdx.x == 0) bsums[blockIdx.x] = s[0];
}

__global__ void scan_bsums(const int* __restrict__ bsums, int* __restrict__ bexcl, int nb) {
    __shared__ int s[512];
    int t = threadIdx.x;
    int v = (t < nb) ? bsums[t] : 0;
    s[t] = v; __syncthreads();
    for (int o = 1; o < 512; o <<= 1) {
        int x = (t >= o) ? s[t - o] : 0;
        __syncthreads();
        s[t] += x;
        __syncthreads();
    }
    if (t < nb) bexcl[t] = s[t] - v;  // exclusive
}

__global__ void scan_offsets(const int* __restrict__ deg, const int* __restrict__ bexcl,
                             int* __restrict__ offs, int n) {
    __shared__ int s[256];
    int t = threadIdx.x;
    int i = blockIdx.x * 256 + t;
    int v = (i < n) ? (deg[i] - 1) : 0;
    s[t] = v; __syncthreads();
    for (int o = 1; o < 256; o <<= 1) {
        int x = (t >= o) ? s[t - o] : 0;
        __syncthreads();
        s[t] += x;
        __syncthreads();
    }
    if (i < n) offs[i] = bexcl[blockIdx.x] + s[t] - v;  // exclusive global offset
}

__global__ void scatter_kernel(const int* __restrict__ srcv, const int* __restrict__ dstv,
                               const int* __restrict__ offs, int* __restrict__ cursor,
                               int* __restrict__ csr, int e) {
    int i4 = (blockIdx.x * blockDim.x + threadIdx.x) * 4;
    if (i4 + 3 < e) {
        v4i sv = nt_ld4i(srcv + i4);
        v4i dv = nt_ld4i(dstv + i4);
        int p;
        p = offs[dv.x] + atomicAdd(&cursor[dv.x], 1); __builtin_nontemporal_store(sv.x, csr + p);
        p = offs[dv.y] + atomicAdd(&cursor[dv.y], 1); __builtin_nontemporal_store(sv.y, csr + p);
        p = offs[dv.z] + atomicAdd(&cursor[dv.z], 1); __builtin_nontemporal_store(sv.z, csr + p);
        p = offs[dv.w] + atomicAdd(&cursor[dv.w], 1); __builtin_nontemporal_store(sv.w, csr + p);
    } else {
        for (int k = i4; k < e; ++k) {
            int d = __builtin_nontemporal_load(dstv + k);
            int p = offs[d] + atomicAdd(&cursor[d], 1);
            __builtin_nontemporal_store(__builtin_nontemporal_load(srcv + k), csr + p);
        }
    }
}

// ---------------- GEMM: out[r] = fp16( (A[r] @ W) * rowscale[r] ), W 128x128 ----------------
template <typename AT>
__global__ __launch_bounds__(1024, 1)
void gemm_nn128(const AT* __restrict__ A, const float* __restrict__ W,
                const float* __restrict__ rowscale, half_t* __restrict__ out,
                int n, int nchunk) {
    __shared__ float Ws[128 * 128];   // [k][j], 64 KiB
    __shared__ float As[128 * 128];   // [r][k], 64 KiB
    constexpr bool HALF = (sizeof(AT) == 2);
    int tid = threadIdx.x;
#pragma unroll
    for (int q = 0; q < 4; ++q)
        ((float4*)Ws)[tid + 1024 * q] = ((const float4*)W)[tid + 1024 * q];

    int tc = tid & 31;
    int tr = tid >> 5;
    int col0 = tc * 4;

    v4i pf[4];
    auto prefetch = [&](int cc) {
        if constexpr (HALF) {
#pragma unroll
            for (int q = 0; q < 2; ++q) {
                int u = tid + 1024 * q;           // 16B unit: 8 halves; 16 units/row
                int row = cc * 128 + (u >> 4);
                if (row > n - 1) row = n - 1;
                pf[q] = nt_ld4i((const int*)((const half_t*)A + (size_t)row * 128 + (u & 15) * 8));
            }
        } else {
#pragma unroll
            for (int q = 0; q < 4; ++q) {
                int fidx = tid + 1024 * q;        // float4 unit; 32 units/row
                int row = cc * 128 + (fidx >> 5);
                if (row > n - 1) row = n - 1;
                pf[q] = nt_ld4i((const int*)((const float*)A + (size_t)row * 128 + (fidx & 31) * 4));
            }
        }
    };

    int c = blockIdx.x;
    if (c < nchunk) prefetch(c);
    for (; c < nchunk; c += gridDim.x) {
        __syncthreads();
        if constexpr (HALF) {
#pragma unroll
            for (int q = 0; q < 2; ++q) {
                int u = tid + 1024 * q;
                int r = u >> 4, cc = (u & 15) * 8;
                H8 hh; hh.v = pf[q];
#pragma unroll
                for (int j = 0; j < 8; ++j) As[r * 128 + cc + j] = (float)hh.h[j];
            }
        } else {
#pragma unroll
            for (int q = 0; q < 4; ++q)
                ((v4i*)As)[tid + 1024 * q] = pf[q];
        }
        __syncthreads();
        if (c + (int)gridDim.x < nchunk) prefetch(c + gridDim.x);
        float4 acc[4];
#pragma unroll
        for (int r = 0; r < 4; ++r) acc[r] = make_float4(0.f, 0.f, 0.f, 0.f);
#pragma unroll 8
        for (int k4 = 0; k4 < 32; ++k4) {
            float4 av[4], wv[4];
#pragma unroll
            for (int r = 0; r < 4; ++r)
                av[r] = ld4(&As[(tr * 4 + r) * 128 + k4 * 4]);
#pragma unroll
            for (int kk = 0; kk < 4; ++kk)
                wv[kk] = ld4(&Ws[(k4 * 4 + kk) * 128 + col0]);
#pragma unroll
            for (int r = 0; r < 4; ++r) {
                acc[r].x += av[r].x * wv[0].x + av[r].y * wv[1].x + av[r].z * wv[2].x + av[r].w * wv[3].x;
                acc[r].y += av[r].x * wv[0].y + av[r].y * wv[1].y + av[r].z * wv[2].y + av[r].w * wv[3].y;
                acc[r].z += av[r].x * wv[0].z + av[r].y * wv[1].z + av[r].z * wv[2].z + av[r].w * wv[3].z;
                acc[r].w += av[r].x * wv[0].w + av[r].y * wv[1].w + av[r].z * wv[2].w + av[r].w * wv[3].w;
            }
        }
#pragma unroll
        for (int r = 0; r < 4; ++r) {
            int row = c * 128 + tr * 4 + r;
            if (row < n) {
                float s = rowscale[row];
                H4 o;
                o.h[0] = (half_t)(acc[r].x * s); o.h[1] = (half_t)(acc[r].y * s);
                o.h[2] = (half_t)(acc[r].z * s); o.h[3] = (half_t)(acc[r].w * s);
                *reinterpret_cast<short4*>(out + (size_t)row * 128 + col0) = o.s;
            }
        }
    }
}

// ---------------- Aggregation: node-parallel over CSR, fp16 rows ----------------
__global__ __launch_bounds__(256)
void agg_kernel(const half_t* __restrict__ hs, const float* __restrict__ dis,
                const int* __restrict__ offs, const int* __restrict__ deg,
                const int* __restrict__ csr, const float* __restrict__ bias,
                half_t* __restrict__ out, int n, int etot) {
    int node = blockIdx.x * 8 + (threadIdx.x >> 5);   // 8 nodes/block, 32 lanes/node
    if (node >= n) return;
    int lane = threadIdx.x & 31;
    int l4 = lane * 4;                                // half-index within row
    float di = dis[node];
    H4 sv; sv.s = ldh4(hs + (size_t)node * 128 + l4);
    float4 acc;
    acc.x = (float)sv.h[0]; acc.y = (float)sv.h[1];
    acc.z = (float)sv.h[2]; acc.w = (float)sv.h[3];
    int st = offs[node];
    int cnt = deg[node] - 1;
    // clamp so no index can ever leave the written region (defense vs any corruption)
    auto clampn = [&](int s) { return ((unsigned)s >= (unsigned)n) ? 0 : s; };
    for (int base = 0; base < cnt; base += 32) {
        int ii = st + base + lane;
        int iv = __builtin_nontemporal_load(csr + (ii < etot ? ii : etot - 1));  // streamed once
        int m = cnt - base; m = m > 32 ? 32 : m;
        int e = 0;
        for (; e + 4 <= m; e += 4) {
            int s0 = clampn(__shfl(iv, e, 32)),     s1 = clampn(__shfl(iv, e + 1, 32));
            int s2 = clampn(__shfl(iv, e + 2, 32)), s3 = clampn(__shfl(iv, e + 3, 32));
            H4 v0, v1, v2, v3;
            v0.s = ldh4(hs + (size_t)s0 * 128 + l4);
            v1.s = ldh4(hs + (size_t)s1 * 128 + l4);
            v2.s = ldh4(hs + (size_t)s2 * 128 + l4);
            v3.s = ldh4(hs + (size_t)s3 * 128 + l4);
            acc.x += ((float)v0.h[0] + (float)v1.h[0]) + ((float)v2.h[0] + (float)v3.h[0]);
            acc.y += ((float)v0.h[1] + (float)v1.h[1]) + ((float)v2.h[1] + (float)v3.h[1]);
            acc.z += ((float)v0.h[2] + (float)v1.h[2]) + ((float)v2.h[2] + (float)v3.h[2]);
            acc.w += ((float)v0.h[3] + (float)v1.h[3]) + ((float)v2.h[3] + (float)v3.h[3]);
        }
        for (; e < m; ++e) {
            int s0 = clampn(__shfl(iv, e, 32));
            H4 v0; v0.s = ldh4(hs + (size_t)s0 * 128 + l4);
            acc.x += (float)v0.h[0]; acc.y += (float)v0.h[1];
            acc.z += (float)v0.h[2]; acc.w += (float)v0.h[3];
        }
    }
    float4 b = ld4(bias + l4);
    float ox = fmaxf(acc.x * di + b.x, 0.f);
    float oy = fmaxf(acc.y * di + b.y, 0.f);
    float oz = fmaxf(acc.z * di + b.z, 0.f);
    float ow = fmaxf(acc.w * di + b.w, 0.f);
    H4 o;
    o.h[0] = (half_t)ox; o.h[1] = (half_t)oy; o.h[2] = (half_t)oz; o.h[3] = (half_t)ow;
    *reinterpret_cast<short4*>(out + (size_t)node * 128 + l4) = o.s;
}

// ---------------- Head: out[n x 40] = A(fp16)[n x 128] @ Wl[128 x 40] + bl ----------------
__global__ __launch_bounds__(256)
void head_kernel(const half_t* __restrict__ A, const float* __restrict__ W,
                 const float* __restrict__ bias, float* __restrict__ out, int n) {
    __shared__ float Ws[128 * 40];   // 20 KiB
    __shared__ float bs[40];
    int tid = threadIdx.x;
#pragma unroll
    for (int q = 0; q < 5; ++q)
        ((float4*)Ws)[tid + 256 * q] = ((const float4*)W)[tid + 256 * q];
    if (tid < 40) bs[tid] = bias[tid];
    __syncthreads();

    int rg = tid >> 3;           // 32 row groups * 2 rows = 64 rows/block
    int c0 = (tid & 7) * 5;      // 8 col groups * 5 = 40 cols
    int row0 = blockIdx.x * 64 + rg * 2;
    int rA = row0 < n ? row0 : n - 1;
    int rB = row0 + 1 < n ? row0 + 1 : n - 1;
    float acc[2][5];
#pragma unroll
    for (int r = 0; r < 2; ++r)
#pragma unroll
        for (int cc = 0; cc < 5; ++cc) acc[r][cc] = 0.f;
#pragma unroll 4
    for (int k4 = 0; k4 < 32; ++k4) {
        H4 a0, a1;
        a0.s = ldh4(A + (size_t)rA * 128 + k4 * 4);
        a1.s = ldh4(A + (size_t)rB * 128 + k4 * 4);
#pragma unroll
        for (int kk = 0; kk < 4; ++kk) {
            int k = k4 * 4 + kk;
            float f0 = (float)a0.h[kk], f1 = (float)a1.h[kk];
#pragma unroll
            for (int cc = 0; cc < 5; ++cc) {
                float w = Ws[k * 40 + c0 + cc];
                acc[0][cc] += f0 * w;
                acc[1][cc] += f1 * w;
            }
        }
    }
#pragma unroll
    for (int r = 0; r < 2; ++r) {
        int row = row0 + r;
        if (row < n) {
#pragma unroll
            for (int cc = 0; cc < 5; ++cc)
                out[(size_t)row * 40 + c0 + cc] = acc[r][cc] + bs[c0 + cc];
        }
    }
}

// ---------------- launch ----------------
extern "C" void kernel_launch(void* const* d_in, const int* in_sizes, int n_in,
                              void* d_out, int out_size, void* d_ws, size_t ws_size,
                              hipStream_t stream) {
    const float* x  = (const float*)d_in[0];
    const int*   ei = (const int*)d_in[1];
    const float* W1 = (const float*)d_in[2];
    const float* b1 = (const float*)d_in[3];
    const float* W2 = (const float*)d_in[4];
    const float* b2 = (const float*)d_in[5];
    const float* Wl = (const float*)d_in[6];
    const float* bl = (const float*)d_in[7];
    float* out = (float*)d_out;

    int n = in_sizes[0] / 128;
    int e = in_sizes[1] / 2;
    const int* srcv = ei;
    const int* dstv = ei + e;

    char* p = (char*)d_ws;
    auto carve = [&](size_t bytes) { char* r = p; p += (bytes + 255) & ~(size_t)255; return r; };
    int*    deg    = (int*)   carve((size_t)n * 4);
    float*  dis    = (float*) carve((size_t)n * 4);
    int*    offs   = (int*)   carve((size_t)n * 4);
    int*    cursor = (int*)   carve((size_t)n * 4);
    int*    bsums  = (int*)   carve(512 * 4);
    int*    bexcl  = (int*)   carve(512 * 4);
    int*    csr    = (int*)   carve((size_t)e * 4);
    half_t* bufA   = (half_t*)carve((size_t)n * 128 * 2);
    half_t* bufB   = (half_t*)carve((size_t)n * 128 * 2);

    int nb = (n + 255) / 256;                 // 391 <= 512
    int nchunk = (n + 127) / 128;
    int e4b = (e / 4 + 255) / 256 + 1;

    hipLaunchKernelGGL(init_kernel, dim3((n + 255) / 256), dim3(256), 0, stream, deg, cursor, n);
    hipLaunchKernelGGL(hist_kernel, dim3(e4b), dim3(256), 0, stream, dstv, deg, e);
    hipLaunchKernelGGL(scan_block_sum, dim3(nb), dim3(256), 0, stream, deg, bsums, dis, n);
    hipLaunchKernelGGL(scan_bsums, dim3(1), dim3(512), 0, stream, bsums, bexcl, nb);
    hipLaunchKernelGGL(scan_offsets, dim3(nb), dim3(256), 0, stream, deg, bexcl, offs, n);
    hipLaunchKernelGGL(scatter_kernel, dim3(e4b), dim3(256), 0, stream,
                       srcv, dstv, offs, cursor, csr, e);

    // layer 1
    hipLaunchKernelGGL(gemm_nn128<float>, dim3(256), dim3(1024), 0, stream,
                       x, W1, dis, bufA, n, nchunk);
    hipLaunchKernelGGL(agg_kernel, dim3((n + 7) / 8), dim3(256), 0, stream,
                       bufA, dis, offs, deg, csr, b1, bufB, n, e);
    // layer 2
    hipLaunchKernelGGL(gemm_nn128<half_t>, dim3(256), dim3(1024), 0, stream,
                       bufB, W2, dis, bufA, n, nchunk);
    hipLaunchKernelGGL(agg_kernel, dim3((n + 7) / 8), dim3(256), 0, stream,
                       bufA, dis, offs, deg, csr, b2, bufB, n, e);
    // head
    hipLaunchKernelGGL(head_kernel, dim3((n + 63) / 64), dim3(256), 0, stream,
                       bufB, Wl, bl, out, n);
}